// Round 1
// baseline (163.003 us; speedup 1.0000x reference)
//
#include <hip/hip_runtime.h>

#define SUBLEN 25   // atoms per sub-fragment
#define GRPSZ  40   // sub-fragments per group  -> ngrp = nsub/GRPSZ

struct Xf { float r[9]; float t[3]; };   // x -> x @ R + t, r = rows

__device__ __forceinline__ Xf xf_identity() {
    Xf o;
    o.r[0]=1.f;o.r[1]=0.f;o.r[2]=0.f;
    o.r[3]=0.f;o.r[4]=1.f;o.r[5]=0.f;
    o.r[6]=0.f;o.r[7]=0.f;o.r[8]=1.f;
    o.t[0]=0.f;o.t[1]=0.f;o.t[2]=0.f;
    return o;
}

// (a∘b)(x) = a(b(x)) = x @ (Rb·Ra) + (tb·Ra + ta)
__device__ __forceinline__ Xf xf_compose(const Xf& a, const Xf& b) {
    Xf o;
#pragma unroll
    for (int i = 0; i < 3; ++i) {
#pragma unroll
        for (int c = 0; c < 3; ++c) {
            o.r[i*3+c] = b.r[i*3+0]*a.r[0+c] + b.r[i*3+1]*a.r[3+c] + b.r[i*3+2]*a.r[6+c];
        }
    }
#pragma unroll
    for (int c = 0; c < 3; ++c)
        o.t[c] = b.t[0]*a.r[0+c] + b.t[1]*a.r[3+c] + b.t[2]*a.r[6+c] + a.t[c];
    return o;
}

__device__ __forceinline__ void xf_store(float* p, const Xf& x) {
    float4* q = (float4*)p;
    q[0] = make_float4(x.r[0], x.r[1], x.r[2], x.r[3]);
    q[1] = make_float4(x.r[4], x.r[5], x.r[6], x.r[7]);
    q[2] = make_float4(x.r[8], x.t[0], x.t[1], x.t[2]);
}

__device__ __forceinline__ Xf xf_load(const float* p) {
    const float4* q = (const float4*)p;
    float4 a = q[0], b = q[1], c = q[2];
    Xf o;
    o.r[0]=a.x; o.r[1]=a.y; o.r[2]=a.z; o.r[3]=a.w;
    o.r[4]=b.x; o.r[5]=b.y; o.r[6]=b.z; o.r[7]=b.w;
    o.r[8]=c.x; o.t[0]=c.y; o.t[1]=c.z; o.t[2]=c.w;
    return o;
}

// One NERF step. State: up = dir(B-A), u = dir(C-B), (cx,cy,cz) = C.
// frame rows = [u, cross(n,u), n], n = normalize(cross(up,u)).
// |D - C| == bond_length exactly (orthonormal frame), so u_next = d / bl.
__device__ __forceinline__ void nerf_step(float bl, float ba, float ph,
    float& upx, float& upy, float& upz,
    float& ux,  float& uy,  float& uz,
    float& cx,  float& cy,  float& cz) {
    float sb, cb, sp, cp;
    __sincosf(ba, &sb, &cb);
    __sincosf(ph, &sp, &cp);
    float px = bl * cb;
    float rs = bl * sb;
    float py = cp * rs;
    float pz = sp * rs;
    float nx = upy*uz - upz*uy;
    float ny = upz*ux - upx*uz;
    float nz = upx*uy - upy*ux;
    float rin = __builtin_amdgcn_rsqf(nx*nx + ny*ny + nz*nz);
    nx *= rin; ny *= rin; nz *= rin;
    float mx = ny*uz - nz*uy;
    float my = nz*ux - nx*uz;
    float mz = nx*uy - ny*ux;
    float dx = px*ux + py*mx + pz*nx;
    float dy = px*uy + py*my + pz*ny;
    float dz = px*uz + py*mz + pz*nz;
    cx += dx; cy += dy; cz += dz;
    float ribl = __builtin_amdgcn_rcpf(bl);
    upx = ux; upy = uy; upz = uz;
    ux = dx*ribl; uy = dy*ribl; uz = dz*ribl;
}

#define UP0X (-0.5f)
#define UP0Y (-0.86602540378443865f)

// K1: per sub-fragment local recursion from INIT; emit link (frame(last3), last point)
__global__ void k_links(const float* __restrict__ inner, float* __restrict__ links, int nsub) {
    int j = blockIdx.x * blockDim.x + threadIdx.x;
    if (j >= nsub) return;
    const float* src = inner + (size_t)j * (SUBLEN * 3);
    float upx = UP0X, upy = UP0Y, upz = 0.f;
    float ux = 1.f, uy = 0.f, uz = 0.f;
    float cx = 0.f, cy = 0.f, cz = 0.f;
    for (int k = 0; k < SUBLEN; ++k) {
        float bl = src[3*k+0], ba = src[3*k+1], ph = src[3*k+2];
        nerf_step(bl, ba, ph, upx, upy, upz, ux, uy, uz, cx, cy, cz);
    }
    // link frame from final (up, u)
    float nx = upy*uz - upz*uy;
    float ny = upz*ux - upx*uz;
    float nz = upx*uy - upy*ux;
    float rin = __builtin_amdgcn_rsqf(nx*nx + ny*ny + nz*nz);
    nx *= rin; ny *= rin; nz *= rin;
    float mx = ny*uz - nz*uy;
    float my = nz*ux - nx*uz;
    float mz = nx*uy - ny*ux;
    Xf L;
    L.r[0]=ux; L.r[1]=uy; L.r[2]=uz;
    L.r[3]=mx; L.r[4]=my; L.r[5]=mz;
    L.r[6]=nx; L.r[7]=ny; L.r[8]=nz;
    L.t[0]=cx; L.t[1]=cy; L.t[2]=cz;
    xf_store(&links[(size_t)j*12], L);
}

// K2a: per group of GRPSZ links: store intra-group exclusive prefixes, emit group link
__global__ void k_group(const float* __restrict__ links, float* __restrict__ Apre,
                        float* __restrict__ glinks, int ngrp) {
    int g = blockIdx.x * blockDim.x + threadIdx.x;
    if (g >= ngrp) return;
    Xf acc = xf_identity();
    for (int k = 0; k < GRPSZ; ++k) {
        size_t j = (size_t)g * GRPSZ + k;
        xf_store(&Apre[j*12], acc);
        Xf L = xf_load(&links[j*12]);
        acc = xf_compose(acc, L);
    }
    xf_store(&glinks[(size_t)g*12], acc);
}

// K2b: single-block Hillis-Steele scan over group links, composed with T0(mainchain).
__global__ void __launch_bounds__(1024) k_scan(const float* __restrict__ glinks,
                                               const float* __restrict__ mc,
                                               float* __restrict__ Tgrp,
                                               float* __restrict__ out, int ngrp) {
    __shared__ __align__(16) float sbuf[1024 * 12];
    int t = threadIdx.x;

    // serial chunk of 3, keep local exclusive prefixes
    Xf acc = xf_identity();
    Xf lp[3];
#pragma unroll
    for (int k = 0; k < 3; ++k) {
        lp[k] = acc;
        int idx = 3*t + k;
        Xf P = xf_identity();
        if (idx < ngrp) P = xf_load(&glinks[(size_t)idx*12]);
        acc = xf_compose(acc, P);
    }
    Xf cur = acc;
    xf_store(&sbuf[t*12], cur);

    for (int d = 1; d < 1024; d <<= 1) {
        __syncthreads();
        Xf p;
        bool has = (t >= d);
        if (has) p = xf_load(&sbuf[(t-d)*12]);
        __syncthreads();
        if (has) {
            cur = xf_compose(p, cur);
            xf_store(&sbuf[t*12], cur);
        }
    }
    __syncthreads();
    Xf E = (t == 0) ? xf_identity() : xf_load(&sbuf[(t-1)*12]);

    // T0 from mainchain rows A,B,C
    float Ax=mc[0], Ay=mc[1], Az=mc[2];
    float Bx=mc[3], By=mc[4], Bz=mc[5];
    float Cx=mc[6], Cy=mc[7], Cz=mc[8];
    float bx = Cx-Bx, by = Cy-By, bz = Cz-Bz;
    float rb = __builtin_amdgcn_rsqf(bx*bx + by*by + bz*bz);
    bx *= rb; by *= rb; bz *= rb;
    float ex = Bx-Ax, ey = By-Ay, ez = Bz-Az;
    float nx = ey*bz - ez*by;
    float ny = ez*bx - ex*bz;
    float nz = ex*by - ey*bx;
    float rn = __builtin_amdgcn_rsqf(nx*nx + ny*ny + nz*nz);
    nx *= rn; ny *= rn; nz *= rn;
    float mx = ny*bz - nz*by;
    float my = nz*bx - nx*bz;
    float mz = nx*by - ny*bx;
    Xf T0;
    T0.r[0]=bx; T0.r[1]=by; T0.r[2]=bz;
    T0.r[3]=mx; T0.r[4]=my; T0.r[5]=mz;
    T0.r[6]=nx; T0.r[7]=ny; T0.r[8]=nz;
    T0.t[0]=Cx; T0.t[1]=Cy; T0.t[2]=Cz;

    Xf base = xf_compose(T0, E);
#pragma unroll
    for (int k = 0; k < 3; ++k) {
        int idx = 3*t + k;
        if (idx < ngrp) {
            Xf T = xf_compose(base, lp[k]);
            xf_store(&Tgrp[(size_t)idx*12], T);
        }
    }
    if (t == 0) {
#pragma unroll
        for (int i = 0; i < 9; ++i) out[i] = mc[i];
    }
}

// K3: recompute sub-fragment recursion with transformed initial state -> global points
__global__ void k_emit(const float* __restrict__ inner, const float* __restrict__ Apre,
                       const float* __restrict__ Tgrp, float* __restrict__ out, int nsub) {
    int j = blockIdx.x * blockDim.x + threadIdx.x;
    if (j >= nsub) return;
    int g = j / GRPSZ;
    Xf A  = xf_load(&Apre[(size_t)j*12]);
    Xf Tg = xf_load(&Tgrp[(size_t)g*12]);
    Xf T  = xf_compose(Tg, A);   // maps this sub-fragment's local coords -> global

    // transformed initial state (equivariance): u = (1,0,0)@R, up = up0@R, C = t
    float ux = T.r[0], uy = T.r[1], uz = T.r[2];
    float upx = UP0X*T.r[0] + UP0Y*T.r[3];
    float upy = UP0X*T.r[1] + UP0Y*T.r[4];
    float upz = UP0X*T.r[2] + UP0Y*T.r[5];
    float cx = T.t[0], cy = T.t[1], cz = T.t[2];

    const float* src = inner + (size_t)j * (SUBLEN * 3);
    float* dst = out + 9 + (size_t)j * (SUBLEN * 3);
    for (int k = 0; k < SUBLEN; ++k) {
        float bl = src[3*k+0], ba = src[3*k+1], ph = src[3*k+2];
        nerf_step(bl, ba, ph, upx, upy, upz, ux, uy, uz, cx, cy, cz);
        dst[3*k+0] = cx; dst[3*k+1] = cy; dst[3*k+2] = cz;
    }
}

extern "C" void kernel_launch(void* const* d_in, const int* in_sizes, int n_in,
                              void* d_out, int out_size, void* d_ws, size_t ws_size,
                              hipStream_t stream) {
    const float* inner = (const float*)d_in[0];
    const float* mc    = (const float*)d_in[2];
    float* out = (float*)d_out;

    int N = in_sizes[0] / 3;          // 3,000,000
    int nsub = N / SUBLEN;            // 120,000
    int ngrp = nsub / GRPSZ;          // 3,000  (fits single-block scan of 3*1024)

    float* links  = (float*)d_ws;                     // nsub*12 floats
    float* Apre   = links + (size_t)nsub * 12;        // nsub*12 floats
    float* glinks = Apre  + (size_t)nsub * 12;        // ngrp*12 floats
    float* Tgrp   = glinks + (size_t)ngrp * 12;       // ngrp*12 floats

    dim3 blk(256);
    k_links<<<(nsub + 255) / 256, blk, 0, stream>>>(inner, links, nsub);
    k_group<<<(ngrp + 255) / 256, blk, 0, stream>>>(links, Apre, glinks, ngrp);
    k_scan<<<1, 1024, 0, stream>>>(glinks, mc, Tgrp, out, ngrp);
    k_emit<<<(nsub + 255) / 256, blk, 0, stream>>>(inner, Apre, Tgrp, out, nsub);
}

// Round 3
// 44.160 us; speedup vs baseline: 3.6912x; 3.6912x over previous
//
#include <hip/hip_runtime.h>

#define NSTEPS 25            // atoms per sub-fragment
#define SUBF   (NSTEPS * 3)  // floats per sub-fragment = 75
#define BLK    256

struct Xf { float m[12]; };  // x -> x @ R + t ; rows = m[0..8], t = m[9..11]

__device__ __forceinline__ Xf xf_identity() {
    Xf o;
    o.m[0]=1.f;o.m[1]=0.f;o.m[2]=0.f;
    o.m[3]=0.f;o.m[4]=1.f;o.m[5]=0.f;
    o.m[6]=0.f;o.m[7]=0.f;o.m[8]=1.f;
    o.m[9]=0.f;o.m[10]=0.f;o.m[11]=0.f;
    return o;
}

// compose(a,b): apply b first, then a.  R = Rb*Ra, t = tb@Ra + ta
__device__ __forceinline__ Xf xf_compose(const Xf& a, const Xf& b) {
    Xf o;
#pragma unroll
    for (int i = 0; i < 3; ++i)
#pragma unroll
        for (int c = 0; c < 3; ++c)
            o.m[i*3+c] = b.m[i*3+0]*a.m[0+c] + b.m[i*3+1]*a.m[3+c] + b.m[i*3+2]*a.m[6+c];
#pragma unroll
    for (int c = 0; c < 3; ++c)
        o.m[9+c] = b.m[9+0]*a.m[0+c] + b.m[9+1]*a.m[3+c] + b.m[9+2]*a.m[6+c] + a.m[9+c];
    return o;
}

__device__ __forceinline__ void xf_store_g(float* p, const Xf& x) {
    float4* q = (float4*)p;
    q[0] = make_float4(x.m[0], x.m[1], x.m[2],  x.m[3]);
    q[1] = make_float4(x.m[4], x.m[5], x.m[6],  x.m[7]);
    q[2] = make_float4(x.m[8], x.m[9], x.m[10], x.m[11]);
}

__device__ __forceinline__ Xf xf_load_g(const float* p) {
    const float4* q = (const float4*)p;
    float4 a = q[0], b = q[1], c = q[2];
    Xf o;
    o.m[0]=a.x; o.m[1]=a.y; o.m[2]=a.z;  o.m[3]=a.w;
    o.m[4]=b.x; o.m[5]=b.y; o.m[6]=b.z;  o.m[7]=b.w;
    o.m[8]=c.x; o.m[9]=c.y; o.m[10]=c.z; o.m[11]=c.w;
    return o;
}

__device__ __forceinline__ Xf xf_shflup(const Xf& x, int d) {
    Xf o;
#pragma unroll
    for (int i = 0; i < 12; ++i) o.m[i] = __shfl_up(x.m[i], d, 64);
    return o;
}

// One NERF step. State: up = dir(B-A), u = dir(C-B), (cx,cy,cz) = C.
// frame rows = [u, cross(n,u), n], n = normalize(cross(up,u)).
// |D - C| == bond_length exactly, so u_next = d / bl (one rcp, no norm).
__device__ __forceinline__ void nerf_step(float bl, float ba, float ph,
    float& upx, float& upy, float& upz,
    float& ux,  float& uy,  float& uz,
    float& cx,  float& cy,  float& cz) {
    float sb, cb, sp, cp;
    __sincosf(ba, &sb, &cb);
    __sincosf(ph, &sp, &cp);
    float px = bl * cb;
    float rs = bl * sb;
    float py = cp * rs;
    float pz = sp * rs;
    float nx = upy*uz - upz*uy;
    float ny = upz*ux - upx*uz;
    float nz = upx*uy - upy*ux;
    float rin = __builtin_amdgcn_rsqf(nx*nx + ny*ny + nz*nz);
    nx *= rin; ny *= rin; nz *= rin;
    float mx = ny*uz - nz*uy;
    float my = nz*ux - nx*uz;
    float mz = nx*uy - ny*ux;
    float dx = px*ux + py*mx + pz*nx;
    float dy = px*uy + py*my + pz*ny;
    float dz = px*uz + py*mz + pz*nz;
    cx += dx; cy += dy; cz += dz;
    float ribl = __builtin_amdgcn_rcpf(bl);
    upx = ux; upy = uy; upz = uz;
    ux = dx*ribl; uy = dy*ribl; uz = dz*ribl;
}

#define UP0X (-0.5f)
#define UP0Y (-0.86602540378443865f)

__device__ __forceinline__ Xf make_T0(const float* __restrict__ mc) {
    float Ax=mc[0], Ay=mc[1], Az=mc[2];
    float Bx=mc[3], By=mc[4], Bz=mc[5];
    float Cx=mc[6], Cy=mc[7], Cz=mc[8];
    float bx = Cx-Bx, by = Cy-By, bz = Cz-Bz;
    float rb = __builtin_amdgcn_rsqf(bx*bx + by*by + bz*bz);
    bx *= rb; by *= rb; bz *= rb;
    float ex = Bx-Ax, ey = By-Ay, ez = Bz-Az;
    float nx = ey*bz - ez*by;
    float ny = ez*bx - ex*bz;
    float nz = ex*by - ey*bx;
    float rn = __builtin_amdgcn_rsqf(nx*nx + ny*ny + nz*nz);
    nx *= rn; ny *= rn; nz *= rn;
    float mx = ny*bz - nz*by;
    float my = nz*bx - nx*bz;
    float mz = nx*by - ny*bx;
    Xf T0;
    T0.m[0]=bx; T0.m[1]=by; T0.m[2]=bz;
    T0.m[3]=mx; T0.m[4]=my; T0.m[5]=mz;
    T0.m[6]=nx; T0.m[7]=ny; T0.m[8]=nz;
    T0.m[9]=Cx; T0.m[10]=Cy; T0.m[11]=Cz;
    return T0;
}

// K1: stage -> local recursion -> intra-block scan -> thread prefixes (SoA) + block link
__global__ void __launch_bounds__(BLK, 2) k_links(
    const float* __restrict__ inner, float* __restrict__ thrPre,
    float* __restrict__ blockLink, int nsub, int nfTot)
{
    __shared__ __align__(16) float data[BLK * SUBF];   // 76800 B
    __shared__ float sc[4 * 12];

    const int tid  = threadIdx.x;
    const int lane = tid & 63;
    const int wv   = tid >> 6;
    const int bid  = blockIdx.x;
    const int j    = bid * BLK + tid;
    const long base_f = (long)bid * (BLK * SUBF);
    int nf = nfTot - (int)base_f;
    if (nf > BLK * SUBF) nf = BLK * SUBF;

    {   // coalesced float4 staging
        const float4* src4 = (const float4*)(inner + base_f);
        float4* dst4 = (float4*)data;
        for (int i4 = tid; i4 < (BLK * SUBF) / 4; i4 += BLK)
            if (i4 * 4 < nf) dst4[i4] = src4[i4];
    }
    __syncthreads();

    Xf L = xf_identity();
    if (j < nsub) {
        float upx=UP0X, upy=UP0Y, upz=0.f;
        float ux=1.f, uy=0.f, uz=0.f;
        float cx=0.f, cy=0.f, cz=0.f;
        const float* src = data + tid * SUBF;
        for (int k = 0; k < NSTEPS; ++k)
            nerf_step(src[3*k], src[3*k+1], src[3*k+2],
                      upx,upy,upz, ux,uy,uz, cx,cy,cz);
        float nx = upy*uz - upz*uy;
        float ny = upz*ux - upx*uz;
        float nz = upx*uy - upy*ux;
        float rin = __builtin_amdgcn_rsqf(nx*nx + ny*ny + nz*nz);
        nx *= rin; ny *= rin; nz *= rin;
        float mx = ny*uz - nz*uy;
        float my = nz*ux - nx*uz;
        float mz = nx*uy - ny*ux;
        L.m[0]=ux; L.m[1]=uy; L.m[2]=uz;
        L.m[3]=mx; L.m[4]=my; L.m[5]=mz;
        L.m[6]=nx; L.m[7]=ny; L.m[8]=nz;
        L.m[9]=cx; L.m[10]=cy; L.m[11]=cz;
    }

    // wave inclusive Kogge-Stone
    Xf incl = L;
#pragma unroll
    for (int d = 1; d < 64; d <<= 1) {
        Xf p = xf_shflup(incl, d);
        if (lane >= d) incl = xf_compose(p, incl);
    }
    Xf laneEx = xf_shflup(incl, 1);
    if (lane == 0) laneEx = xf_identity();

    if (lane == 63) {
#pragma unroll
        for (int i = 0; i < 12; ++i) sc[wv*12 + i] = incl.m[i];
    }
    __syncthreads();

    Xf waveEx = xf_identity();
    for (int w = 0; w < wv; ++w) {
        Xf s;
#pragma unroll
        for (int i = 0; i < 12; ++i) s.m[i] = sc[w*12 + i];
        waveEx = xf_compose(waveEx, s);
    }
    Xf thrEx = xf_compose(waveEx, laneEx);

    if (j < nsub) {
#pragma unroll
        for (int i = 0; i < 12; ++i) thrPre[(size_t)i * nsub + j] = thrEx.m[i];
    }
    if (tid == 0) {
        Xf bt;
#pragma unroll
        for (int i = 0; i < 12; ++i) bt.m[i] = sc[i];
        for (int w = 1; w < 4; ++w) {
            Xf s;
#pragma unroll
            for (int i = 0; i < 12; ++i) s.m[i] = sc[w*12 + i];
            bt = xf_compose(bt, s);
        }
        xf_store_g(blockLink + (size_t)bid * 12, bt);
    }
}

// K2: single block scans NB block links, folds in T0, writes global block prefixes.
__global__ void __launch_bounds__(BLK) k_scan(
    const float* __restrict__ blockLink, const float* __restrict__ mc,
    float* __restrict__ blockPrefix, float* __restrict__ out, int NB)
{
    __shared__ float sc[4 * 12];
    const int tid  = threadIdx.x;
    const int lane = tid & 63;
    const int wv   = tid >> 6;

    int i0 = 2*tid, i1 = 2*tid + 1;
    Xf e0 = (i0 < NB) ? xf_load_g(blockLink + (size_t)i0*12) : xf_identity();
    Xf e1 = (i1 < NB) ? xf_load_g(blockLink + (size_t)i1*12) : xf_identity();
    Xf pin = xf_compose(e0, e1);

    Xf inc2 = pin;
#pragma unroll
    for (int d = 1; d < 64; d <<= 1) {
        Xf p = xf_shflup(inc2, d);
        if (lane >= d) inc2 = xf_compose(p, inc2);
    }
    Xf pl = xf_shflup(inc2, 1);
    if (lane == 0) pl = xf_identity();
    if (lane == 63) {
#pragma unroll
        for (int i = 0; i < 12; ++i) sc[wv*12 + i] = inc2.m[i];
    }
    __syncthreads();
    Xf wex = xf_identity();
    for (int w = 0; w < wv; ++w) {
        Xf s;
#pragma unroll
        for (int i = 0; i < 12; ++i) s.m[i] = sc[w*12 + i];
        wex = xf_compose(wex, s);
    }

    Xf T0 = make_T0(mc);
    Xf g0 = xf_compose(xf_compose(T0, wex), pl);   // global prefix for i0
    Xf g1 = xf_compose(g0, e0);                    // global prefix for i1
    if (i0 < NB) xf_store_g(blockPrefix + (size_t)i0*12, g0);
    if (i1 < NB) xf_store_g(blockPrefix + (size_t)i1*12, g1);

    if (tid == 0) {
#pragma unroll
        for (int i = 0; i < 9; ++i) out[i] = mc[i];
    }
}

// K3: stage -> T = blockPrefix∘threadPrefix -> recompute recursion in LDS -> flush
__global__ void __launch_bounds__(BLK, 2) k_emit(
    const float* __restrict__ inner, const float* __restrict__ thrPre,
    const float* __restrict__ blockPrefix, float* __restrict__ out,
    int nsub, int nfTot)
{
    __shared__ __align__(16) float data[BLK * SUBF];

    const int tid  = threadIdx.x;
    const int bid  = blockIdx.x;
    const int j    = bid * BLK + tid;
    const long base_f = (long)bid * (BLK * SUBF);
    int nf = nfTot - (int)base_f;
    if (nf > BLK * SUBF) nf = BLK * SUBF;

    {
        const float4* src4 = (const float4*)(inner + base_f);
        float4* dst4 = (float4*)data;
        for (int i4 = tid; i4 < (BLK * SUBF) / 4; i4 += BLK)
            if (i4 * 4 < nf) dst4[i4] = src4[i4];
    }
    __syncthreads();

    if (j < nsub) {
        Xf bp = xf_load_g(blockPrefix + (size_t)bid * 12);
        Xf te;
#pragma unroll
        for (int i = 0; i < 12; ++i) te.m[i] = thrPre[(size_t)i * nsub + j];
        Xf T = xf_compose(bp, te);

        float ux = T.m[0], uy = T.m[1], uz = T.m[2];
        float upx = UP0X*T.m[0] + UP0Y*T.m[3];
        float upy = UP0X*T.m[1] + UP0Y*T.m[4];
        float upz = UP0X*T.m[2] + UP0Y*T.m[5];
        float cx = T.m[9], cy = T.m[10], cz = T.m[11];
        float* s = data + tid * SUBF;
        for (int k = 0; k < NSTEPS; ++k) {
            float bl = s[3*k], ba = s[3*k+1], ph = s[3*k+2];
            nerf_step(bl, ba, ph, upx,upy,upz, ux,uy,uz, cx,cy,cz);
            s[3*k] = cx; s[3*k+1] = cy; s[3*k+2] = cz;
        }
    }
    __syncthreads();

    {   // coalesced flush (out+9 breaks 16B alignment -> dword stores)
        float* dst = out + 9 + base_f;
        for (int i = tid; i < nf; i += BLK) dst[i] = data[i];
    }
}

extern "C" void kernel_launch(void* const* d_in, const int* in_sizes, int n_in,
                              void* d_out, int out_size, void* d_ws, size_t ws_size,
                              hipStream_t stream) {
    const float* inner = (const float*)d_in[0];
    const float* mc    = (const float*)d_in[2];
    float* out = (float*)d_out;

    int nfTot = in_sizes[0];             // 9,000,000 floats
    int N     = nfTot / 3;               // 3,000,000 atoms
    int nsub  = N / NSTEPS;              // 120,000 sub-fragments
    int NB    = (nsub + BLK - 1) / BLK;  // 469 blocks (NB <= 512 for K2's 2/lane scan)

    float* thrPre      = (float*)d_ws;                   // 12*nsub floats (SoA)
    float* blockLink   = thrPre + (size_t)12 * nsub;     // NB*12 floats
    float* blockPrefix = blockLink + (size_t)NB * 12;    // NB*12 floats

    k_links<<<NB, BLK, 0, stream>>>(inner, thrPre, blockLink, nsub, nfTot);
    k_scan<<<1, BLK, 0, stream>>>(blockLink, mc, blockPrefix, out, NB);
    k_emit<<<NB, BLK, 0, stream>>>(inner, thrPre, blockPrefix, out, nsub, nfTot);
}